// Round 3
// baseline (238.485 us; speedup 1.0000x reference)
//
#include <hip/hip_runtime.h>

#define DIM    2048
#define SEQ    4096
#define BATCH  4
#define KW     4
#define TCHUNK 16

typedef float fvec4 __attribute__((ext_vector_type(4)));  // native vector for builtins

// One thread: 4 consecutive channels (float4) x TCHUNK timesteps.
// A/B vs R0: identical structure, PLAIN stores instead of nontemporal.
// Evidence: R0/R1/R2 (three different structures) all froze at 83-85 us with
// write rate pinned at 1.6-1.9 TB/s -- the shared element was the nt-store
// path. Theory: nt bypasses L2 allocation, so 16B/lane stores reach HBM as
// partial-line bursts (~25-50% bus efficiency); plain stores let TCC
// accumulate full dirty lines and write back at full burst efficiency.
__global__ __launch_bounds__(256) void ShortConv1D_78855599554935_kernel(
    const float* __restrict__ x, const float* __restrict__ w,
    const float* __restrict__ bias, float* __restrict__ out)
{
    constexpr int D4 = DIM / 4;        // 512 float4 columns
    constexpr int NT = SEQ / TCHUNK;   // 256 time chunks

    int idx  = blockIdx.x * blockDim.x + threadIdx.x;
    int d4   = idx & (D4 - 1);         // % 512
    int rest = idx >> 9;               // / 512
    int tc   = rest & (NT - 1);        // % 256
    int bb   = rest >> 8;              // / 256

    const fvec4* __restrict__ x4 = (const fvec4*)x;
    const fvec4* __restrict__ w4 = (const fvec4*)w;
    const fvec4* __restrict__ b4 = (const fvec4*)bias;
    fvec4* __restrict__ o4 = (fvec4*)out;

    long base = ((long)bb * SEQ + (long)tc * TCHUNK) * D4 + d4;  // fvec4 units

    // ---- Phase 1: independent loads into register array ----
    fvec4 xv[TCHUNK + 3];
    if (tc > 0) {                      // wave-uniform branch (D4=512 >= 64)
        xv[0] = x4[base - 3 * D4];
        xv[1] = x4[base - 2 * D4];
        xv[2] = x4[base - 1 * D4];
    } else {
        xv[0] = (fvec4)(0.f);
        xv[1] = (fvec4)(0.f);
        xv[2] = (fvec4)(0.f);
    }
#pragma unroll
    for (int t = 0; t < TCHUNK; ++t) {
        xv[3 + t] = x4[base + t * D4];
    }

    // weight rows for channels d = 4*d4 + j  (w is [D,K] row-major, K=4)
    fvec4 w0 = w4[d4 * 4 + 0];
    fvec4 w1 = w4[d4 * 4 + 1];
    fvec4 w2 = w4[d4 * 4 + 2];
    fvec4 w3 = w4[d4 * 4 + 3];
    fvec4 bv = b4[d4];

    // ---- Phase 2: compute + plain (L2-allocating) stores ----
#pragma unroll
    for (int t = 0; t < TCHUNK; ++t) {
        fvec4 a  = xv[t];       // x[t-3]
        fvec4 bq = xv[t + 1];   // x[t-2]
        fvec4 c  = xv[t + 2];   // x[t-1]
        fvec4 dd = xv[t + 3];   // x[t]
        fvec4 r;
        r.x = bv.x + w0.x * a.x + w0.y * bq.x + w0.z * c.x + w0.w * dd.x;
        r.y = bv.y + w1.x * a.y + w1.y * bq.y + w1.z * c.y + w1.w * dd.y;
        r.z = bv.z + w2.x * a.z + w2.y * bq.z + w2.z * c.z + w2.w * dd.z;
        r.w = bv.w + w3.x * a.w + w3.y * bq.w + w3.z * c.w + w3.w * dd.w;
        o4[base + t * D4] = r;
    }
}

extern "C" void kernel_launch(void* const* d_in, const int* in_sizes, int n_in,
                              void* d_out, int out_size, void* d_ws, size_t ws_size,
                              hipStream_t stream) {
    const float* x = (const float*)d_in[0];
    const float* w = (const float*)d_in[1];
    const float* b = (const float*)d_in[2];
    float* out = (float*)d_out;

    constexpr int D4 = DIM / 4;
    constexpr int NT = SEQ / TCHUNK;
    int total_threads = BATCH * NT * D4;        // 524288
    int block = 256;
    int grid = total_threads / block;           // 2048

    ShortConv1D_78855599554935_kernel<<<grid, block, 0, stream>>>(x, w, b, out);
}

// Round 4
// 236.222 us; speedup vs baseline: 1.0096x; 1.0096x over previous
//
#include <hip/hip_runtime.h>

#define DIM    2048
#define SEQ    4096
#define BATCH  4
#define KW     4
#define TCHUNK 16

typedef float fvec4 __attribute__((ext_vector_type(4)));  // native vector for builtins

// One thread: 4 consecutive channels (float4) x TCHUNK timesteps.
// A/B vs R3: identical geometry; the ONLY change is an asm keep-alive pin on
// all 19 loaded float4s. Evidence chain: read stream runs at 0.93 TB/s while
// fill proves write path >=6.5 TB/s and copy proves read path >=3.15 TB/s.
// VGPR_Count=32 shows the compiler rolls the 19 loads through ~3 registers
// (vmcnt-serialized reuse -> ~3 loads in flight -> outstanding/latency
// ~ 1 B/cyc/CU ~ the observed 0.93 TB/s). The pin forces all 19 destinations
// live at once: the compiler must issue all loads before the first consume.
__global__ __launch_bounds__(256) void ShortConv1D_78855599554935_kernel(
    const float* __restrict__ x, const float* __restrict__ w,
    const float* __restrict__ bias, float* __restrict__ out)
{
    constexpr int D4 = DIM / 4;        // 512 float4 columns
    constexpr int NT = SEQ / TCHUNK;   // 256 time chunks

    int idx  = blockIdx.x * blockDim.x + threadIdx.x;
    int d4   = idx & (D4 - 1);         // % 512
    int rest = idx >> 9;               // / 512
    int tc   = rest & (NT - 1);        // % 256
    int bb   = rest >> 8;              // / 256

    const fvec4* __restrict__ x4 = (const fvec4*)x;
    const fvec4* __restrict__ w4 = (const fvec4*)w;
    const fvec4* __restrict__ b4 = (const fvec4*)bias;
    fvec4* __restrict__ o4 = (fvec4*)out;

    long base = ((long)bb * SEQ + (long)tc * TCHUNK) * D4 + d4;  // fvec4 units

    // weight rows first (small, L2-hot, drain earliest in vmcnt order)
    fvec4 w0 = w4[d4 * 4 + 0];
    fvec4 w1 = w4[d4 * 4 + 1];
    fvec4 w2 = w4[d4 * 4 + 2];
    fvec4 w3 = w4[d4 * 4 + 3];
    fvec4 bv = b4[d4];

    // ---- Phase 1: issue ALL 19 x-loads ----
    fvec4 xv[TCHUNK + 3];
    if (tc > 0) {                      // wave-uniform branch (D4=512 >= 64)
        xv[0] = x4[base - 3 * D4];
        xv[1] = x4[base - 2 * D4];
        xv[2] = x4[base - 1 * D4];
    } else {
        xv[0] = (fvec4)(0.f);
        xv[1] = (fvec4)(0.f);
        xv[2] = (fvec4)(0.f);
    }
#pragma unroll
    for (int t = 0; t < TCHUNK; ++t) {
        xv[3 + t] = x4[base + t * D4];
    }

    // Pin every loaded value into a live VGPR quad: the register allocator can
    // no longer collapse the window into a 3-register rolling schedule. All 19
    // loads are outstanding together; the waitcnt ladder drains them in order.
#pragma unroll
    for (int i = 0; i < TCHUNK + 3; ++i) {
        asm volatile("" : "+v"(xv[i]));
    }
    __builtin_amdgcn_sched_barrier(0);  // and no load may sink below this point

    // ---- Phase 2: compute + plain stores (register-only inputs) ----
#pragma unroll
    for (int t = 0; t < TCHUNK; ++t) {
        fvec4 a  = xv[t];       // x[t-3]
        fvec4 bq = xv[t + 1];   // x[t-2]
        fvec4 c  = xv[t + 2];   // x[t-1]
        fvec4 dd = xv[t + 3];   // x[t]
        fvec4 r;
        r.x = bv.x + w0.x * a.x + w0.y * bq.x + w0.z * c.x + w0.w * dd.x;
        r.y = bv.y + w1.x * a.y + w1.y * bq.y + w1.z * c.y + w1.w * dd.y;
        r.z = bv.z + w2.x * a.z + w2.y * bq.z + w2.z * c.z + w2.w * dd.z;
        r.w = bv.w + w3.x * a.w + w3.y * bq.w + w3.z * c.w + w3.w * dd.w;
        o4[base + t * D4] = r;
    }
}

extern "C" void kernel_launch(void* const* d_in, const int* in_sizes, int n_in,
                              void* d_out, int out_size, void* d_ws, size_t ws_size,
                              hipStream_t stream) {
    const float* x = (const float*)d_in[0];
    const float* w = (const float*)d_in[1];
    const float* b = (const float*)d_in[2];
    float* out = (float*)d_out;

    constexpr int D4 = DIM / 4;
    constexpr int NT = SEQ / TCHUNK;
    int total_threads = BATCH * NT * D4;        // 524288
    int block = 256;
    int grid = total_threads / block;           // 2048

    ShortConv1D_78855599554935_kernel<<<grid, block, 0, stream>>>(x, w, b, out);
}